// Round 16
// baseline (545.777 us; speedup 1.0000x reference)
//
#include <hip/hip_runtime.h>
#include <cstdint>
#include <cstddef>

#define N_TOK 8192
#define DIM   1024
#define HID   4096
#define DOUT  1024
#define NEXP  8

typedef short  s16x8 __attribute__((ext_vector_type(8)));
typedef __bf16 b16x8 __attribute__((ext_vector_type(8)));
typedef float  f32x4 __attribute__((ext_vector_type(4)));

__device__ __forceinline__ unsigned short f2bf(float f) {
  unsigned u = __float_as_uint(f);
  u += 0x7fffu + ((u >> 16) & 1u);
  return (unsigned short)(u >> 16);
}

__device__ __forceinline__ float bf2f(unsigned short u) {
  return __uint_as_float((unsigned)u << 16);
}

// tanh-form GELU via one fast exp: max |err| vs exact erf-GELU ~3e-4,
// 25x below bf16 quantization of h.
__device__ __forceinline__ float gelu_fast(float v) {
  float u2 = v * (1.5957691216f + 0.0713548163f * v * v);
  return v / (1.0f + __expf(-u2));
}

// async global->LDS, 16B per lane. LDS dest wave-uniform base; HW writes
// lane i at base + i*16. Global src is per-lane (enables source pre-swizzle).
__device__ __forceinline__ void gl_lds16(const void* g, void* l) {
  auto gp = (__attribute__((address_space(1))) void*)(reinterpret_cast<uintptr_t>(g));
  auto lp = (__attribute__((address_space(3))) void*)(reinterpret_cast<uintptr_t>(l));
  __builtin_amdgcn_global_load_lds(gp, lp, 16, 0, 0);
}

// ---------------- transpose+cast: 128x64 tiles, 256B segments both sides ---
__global__ void transpose_cast_kernel(const float* __restrict__ W1,
                                      const float* __restrict__ W2,
                                      const float* __restrict__ sW,
                                      unsigned short* __restrict__ W1t,
                                      unsigned short* __restrict__ W2t,
                                      unsigned short* __restrict__ sWt) {
  int bid = blockIdx.x;
  const float* src;
  unsigned short* dst;
  int R, C, by, bx;
  if (bid < 4096) {                 // W1: [1024][4096], 8x64 tiles/expert
    int e = bid >> 9, t2 = bid & 511;
    src = W1 + (size_t)e * DIM * HID;
    dst = W1t + (size_t)e * DIM * HID;
    R = DIM; C = HID; by = t2 >> 6; bx = t2 & 63;
  } else if (bid < 8192) {          // W2: [4096][1024], 32x16 tiles/expert
    int b2 = bid - 4096;
    int e = b2 >> 9, t2 = b2 & 511;
    src = W2 + (size_t)e * HID * DOUT;
    dst = W2t + (size_t)e * HID * DOUT;
    R = HID; C = DOUT; by = t2 >> 4; bx = t2 & 15;
  } else {                          // sW: [1024][1024], 8x16 tiles
    int t2 = bid - 8192;
    src = sW; dst = sWt;
    R = DIM; C = DOUT; by = t2 >> 4; bx = t2 & 15;
  }
  int r0 = by * 128, c0 = bx * 64;

  __shared__ unsigned short tile[128][66];
  int t = threadIdx.x;

  const float* sp = src + (size_t)r0 * C + c0;
  int rr = t >> 4;
  int rc = (t & 15) * 4;
#pragma unroll
  for (int p = 0; p < 8; ++p) {
    int r = rr + p * 16;
    float4 v = *reinterpret_cast<const float4*>(sp + (size_t)r * C + rc);
    ushort4 o;
    o.x = f2bf(v.x); o.y = f2bf(v.y); o.z = f2bf(v.z); o.w = f2bf(v.w);
    *reinterpret_cast<ushort4*>(&tile[r][rc]) = o;
  }
  __syncthreads();

  unsigned short* dp = dst + (size_t)c0 * R + r0;
  int wc = t >> 5;
  int wr = (t & 31) * 4;
#pragma unroll
  for (int p = 0; p < 8; ++p) {
    int c = wc + p * 8;
    ushort4 o;
    o.x = tile[wr + 0][c];
    o.y = tile[wr + 1][c];
    o.z = tile[wr + 2][c];
    o.w = tile[wr + 3][c];
    *reinterpret_cast<ushort4*>(dp + (size_t)c * R + wr) = o;
  }
}

// ---------------- gate: one wave/token, vectorized, NO atomics -------------
__global__ void gate_kernel(const float* __restrict__ x,
                            const float* __restrict__ gw,
                            unsigned short* __restrict__ xbf,
                            int* __restrict__ topk_e,
                            float* __restrict__ topk_w) {
  int w = threadIdx.x >> 6, lane = threadIdx.x & 63;
  int t = blockIdx.x * 4 + w;
  const float4* xr = reinterpret_cast<const float4*>(x + (size_t)t * DIM);
  ushort4* xo = reinterpret_cast<ushort4*>(xbf + (size_t)t * DIM);
  float a0 = 0.f, a1 = 0.f, a2 = 0.f, a3 = 0.f;
  float a4 = 0.f, a5 = 0.f, a6 = 0.f, a7 = 0.f;
#pragma unroll
  for (int i = 0; i < 4; ++i) {
    int q = lane + (i << 6);
    float4 v = xr[q];
    ushort4 o;
    o.x = f2bf(v.x); o.y = f2bf(v.y); o.z = f2bf(v.z); o.w = f2bf(v.w);
    xo[q] = o;
    const float4* g = reinterpret_cast<const float4*>(gw + (size_t)q * 32);
    float4 g0 = g[0], g1 = g[1], g2 = g[2], g3 = g[3];
    float4 g4 = g[4], g5 = g[5], g6 = g[6], g7 = g[7];
    a0 += v.x * g0.x + v.y * g2.x + v.z * g4.x + v.w * g6.x;
    a1 += v.x * g0.y + v.y * g2.y + v.z * g4.y + v.w * g6.y;
    a2 += v.x * g0.z + v.y * g2.z + v.z * g4.z + v.w * g6.z;
    a3 += v.x * g0.w + v.y * g2.w + v.z * g4.w + v.w * g6.w;
    a4 += v.x * g1.x + v.y * g3.x + v.z * g5.x + v.w * g7.x;
    a5 += v.x * g1.y + v.y * g3.y + v.z * g5.y + v.w * g7.y;
    a6 += v.x * g1.z + v.y * g3.z + v.z * g5.z + v.w * g7.z;
    a7 += v.x * g1.w + v.y * g3.w + v.z * g5.w + v.w * g7.w;
  }
  float acc[8] = {a0, a1, a2, a3, a4, a5, a6, a7};
#pragma unroll
  for (int o = 32; o; o >>= 1)
#pragma unroll
    for (int e = 0; e < 8; ++e) acc[e] += __shfl_down(acc[e], o);
  if (lane == 0) {
    int e0 = 0;
#pragma unroll
    for (int e = 1; e < 8; ++e) if (acc[e] > acc[e0]) e0 = e;
    int e1 = -1;
#pragma unroll
    for (int e = 0; e < 8; ++e) {
      if (e == e0) continue;
      if (e1 < 0 || acc[e] > acc[e1]) e1 = e;
    }
    float w0 = 1.0f / (1.0f + expf(acc[e1] - acc[e0]));  // == p0/(p0+p1)
    topk_e[t * 2 + 0] = e0;
    topk_e[t * 2 + 1] = e1;
    topk_w[t * 2 + 0] = w0;
    topk_w[t * 2 + 1] = 1.0f - w0;
  }
}

// per-block expert counts (LDS-privatized; zero global atomics)
__global__ void count_kernel(const int* __restrict__ topk_e,
                             int* __restrict__ bc) {  // [32][8]
  __shared__ int cnt[8];
  int t = threadIdx.x;
  if (t < 8) cnt[t] = 0;
  __syncthreads();
  int s = blockIdx.x * 512 + t * 2;
  atomicAdd(&cnt[topk_e[s]], 1);
  atomicAdd(&cnt[topk_e[s + 1]], 1);
  __syncthreads();
  if (t < 8) bc[blockIdx.x * 8 + t] = cnt[t];
}

// scan: per-expert offsets + absolute per-(block,expert) bases
__global__ void offsets_kernel(const int* __restrict__ bc,      // [32][8]
                               int* __restrict__ offs,          // [9]
                               int* __restrict__ blockbase) {   // [32][8]
  __shared__ int pre[32][8];
  __shared__ int tot[8];
  __shared__ int soff[9];
  int t = threadIdx.x;  // 256
  if (t < 8) {
    int run = 0;
    for (int b = 0; b < 32; ++b) { pre[b][t] = run; run += bc[b * 8 + t]; }
    tot[t] = run;
  }
  __syncthreads();
  if (t == 0) {
    int o = 0;
    for (int e = 0; e < 8; ++e) { soff[e] = o; offs[e] = o; o += tot[e]; }
    soff[8] = o; offs[8] = o;
  }
  __syncthreads();
  int b = t >> 3, e = t & 7;
  blockbase[t] = soff[e] + pre[b][e];
}

// scatter with LDS-local ranks (8 LDS counters/block; no global atomics)
__global__ void scatter_kernel(const int* __restrict__ topk_e,
                               const int* __restrict__ blockbase,
                               int* __restrict__ rowmap,
                               int* __restrict__ inv) {
  __shared__ int cnt[8];
  int t = threadIdx.x;
  if (t < 8) cnt[t] = 0;
  __syncthreads();
  int s = blockIdx.x * 512 + t * 2;
#pragma unroll
  for (int k = 0; k < 2; ++k) {
    int e = topk_e[s + k];
    int r = atomicAdd(&cnt[e], 1);  // LDS atomic (fast, block-local)
    int p = blockbase[blockIdx.x * 8 + e] + r;
    rowmap[p] = s + k;
    inv[s + k] = p;
  }
}

// ---------------- MFMA GEMM (256x128 tile, BK=32, ring-3, T2+T5) -----------
// R16: 4 waves (2M x 2N), per-wave output 128x64 (acc[8][4] f32x4 = 128
// VGPR). LDS-port arithmetic (R15): per-wave bytes/FLOP drops 25%
// ((128+64)/(128*64) vs (64+64)/(64*64)) -> per pair-iteration LDS ~1321 cy
// vs MFMA 1242 cy (balanced; was 1734 LDS-bound).
// Staging: 6 gl_lds/wave (4 A-groups of 16 rows + 2 B-groups); fence becomes
// vmcnt(6): steady-state queue [stage(kt+1) 6, stage(kt+2) 6] -> retires
// stage(kt+1) (RAW), keeps stage(kt+2) in flight; lgkmcnt(0) drains my
// buf[cur] reads (WAR). Ledger otherwise identical to R13/R14's verified one.
// K-loop unrolled x3 (ring period): compile-time buffer indices.
// T2 swizzle both-sides (zero bank conflicts); T5 setprio around MFMA.
// MODE 0: expert GEMM1 (gathered A rows, epi gelu->bf16) PLUS, for
//         bid >= expGrid, the dense shared GEMM (0.5*gelu->bf16) tail.
// MODE 1: expert GEMM2, compact A (h), epi: out[slot] = w*(acc+b2) -> bf16
template <int MODE>
__global__ __launch_bounds__(256, 2) void gemm_mfma(
    const unsigned short* __restrict__ A,
    const unsigned short* __restrict__ Ball,
    const float* __restrict__ biasAll,
    unsigned short* __restrict__ outAll,
    const int* __restrict__ rowmap,
    const int* __restrict__ offsets,
    const float* __restrict__ topkw,
    int K, int Ncols, int MT, int NT,
    int expGrid, const unsigned short* __restrict__ sB,
    const float* __restrict__ sBias, unsigned short* __restrict__ sOut,
    int M2) {
  int bid = blockIdx.x;
  int mt, nt, rowBase, cnt, ncols, gath;
  float scale;
  const unsigned short* Bp;
  const float* bias;
  unsigned short* outp;
  if (MODE == 0 && bid >= expGrid) {
    int b2 = bid - expGrid;
    int lg = (b2 & 7) * 32 + (b2 >> 3);
    mt = lg >> 3; nt = lg & 7;
    rowBase = 0; cnt = M2; gath = 0; scale = 0.5f;
    Bp = sB; bias = sBias; outp = sOut; ncols = DOUT;
  } else {
    int e = bid & 7;            // expert -> XCD pinning
    int idx = bid >> 3;
    if (MODE == 0) {
      int per = MT * 8;         // 8-nt band over all mt
      int band = idx / per;
      int r2 = idx - band * per;
      mt = r2 >> 3;
      nt = band * 8 + (r2 & 7);
      gath = 2; scale = 1.0f;
    } else {
      mt = idx >> 3; nt = idx & 7;  // NT == 8
      gath = 1; scale = 1.0f;
    }
    rowBase = offsets[e];
    cnt = offsets[e + 1] - rowBase;
    if (mt * 256 >= cnt) return;
    Bp = Ball + (size_t)e * Ncols * K;
    bias = biasAll + (size_t)e * Ncols;
    outp = outAll; ncols = Ncols;
  }

  int t = threadIdx.x;
  int w = t >> 6, lane = t & 63;
  int wm = w >> 1, wn = w & 1;      // 2 x 2 wave grid; per-wave 128x64
  int fr = lane & 15, fg = lane >> 4;

  __shared__ __attribute__((aligned(16))) unsigned short As[3][256][32];
  __shared__ __attribute__((aligned(16))) unsigned short Bs[3][128][32];

  // staging: lane covers row base+(lane>>2); physical chunk (lane&3) gets
  // logical chunk (lane&3)^((lane>>3)&3) (row bases are x16 -> same form).
  int srow = lane >> 2;
  int kch = ((lane & 3) ^ ((lane >> 3) & 3)) * 8;  // element offset (swz)
  const unsigned short* aS[4];
#pragma unroll
  for (int j = 0; j < 4; ++j) {
    int g = mt * 256 + w * 64 + j * 16 + srow;
    int c = g < cnt ? g : cnt - 1;
    size_t ar;
    if (gath == 0)      ar = (size_t)g;
    else if (gath == 1) ar = (size_t)(rowBase + c);
    else                ar = (size_t)(rowmap[rowBase + c] >> 1);
    aS[j] = A + ar * (size_t)K + kch;
  }
  const unsigned short* bS0 = Bp + (size_t)(nt * 128 + w * 32 + srow) * K + kch;
  const unsigned short* bS1 = bS0 + (size_t)16 * K;

  auto stage = [&](int buf, int kt) {
    int ko = kt * 32;
    gl_lds16(aS[0] + ko, &As[buf][w * 64][0]);
    gl_lds16(aS[1] + ko, &As[buf][w * 64 + 16][0]);
    gl_lds16(aS[2] + ko, &As[buf][w * 64 + 32][0]);
    gl_lds16(aS[3] + ko, &As[buf][w * 64 + 48][0]);
    gl_lds16(bS0 + ko, &Bs[buf][w * 32][0]);
    gl_lds16(bS1 + ko, &Bs[buf][w * 32 + 16][0]);
  };

  f32x4 acc[8][4] = {};
  int KT = K >> 5;  // 32 or 128; both == 2 mod 3
  int swc = (fg ^ ((fr >> 1) & 3)) * 8;  // swizzled read chunk (elements)

#define ITER(CUR, NXT, KT_VAL)                                                 \
  {                                                                            \
    int kt_ = (KT_VAL);                                                        \
    if (kt_ + 2 < KT) stage(NXT, kt_ + 2);                                     \
    s16x8 af[8], bf[4];                                                        \
    _Pragma("unroll") for (int m = 0; m < 8; ++m)                              \
        af[m] = *reinterpret_cast<const s16x8*>(                               \
            &As[CUR][wm * 128 + m * 16 + fr][swc]);                            \
    _Pragma("unroll") for (int n = 0; n < 4; ++n)                              \
        bf[n] = *reinterpret_cast<const s16x8*>(                               \
            &Bs[CUR][wn * 64 + n * 16 + fr][swc]);                             \
    __builtin_amdgcn_s_setprio(1);                                             \
    _Pragma("unroll") for (int m = 0; m < 8; ++m)                              \
        _Pragma("unroll") for (int n = 0; n < 4; ++n)                          \
            acc[m][n] = __builtin_amdgcn_mfma_f32_16x16x32_bf16(               \
                __builtin_bit_cast(b16x8, af[m]),                              \
                __builtin_bit_cast(b16x8, bf[n]), acc[m][n], 0, 0, 0);         \
    __builtin_amdgcn_s_setprio(0);                                             \
    if (kt_ + 2 < KT)                                                          \
      asm volatile("s_waitcnt vmcnt(6) lgkmcnt(0)" ::: "memory");              \
    else                                                                       \
      asm volatile("s_waitcnt vmcnt(0) lgkmcnt(0)" ::: "memory");              \
    __builtin_amdgcn_s_barrier();                                              \
  }

  // prologue: stage(0), stage(1) (12 loads); vmcnt(6) -> buf0 landed.
  stage(0, 0);
  stage(1, 1);
  asm volatile("s_waitcnt vmcnt(6)" ::: "memory");
  __builtin_amdgcn_s_barrier();

  int kt = 0;
  for (; kt + 3 <= KT; kt += 3) {
    ITER(0, 2, kt)
    ITER(1, 0, kt + 1)
    ITER(2, 1, kt + 2)
  }
  // tail: exactly 2 iterations (KT % 3 == 2), ring phase continues 0,1
  ITER(0, 2, KT - 2)
  ITER(1, 0, KT - 1)
#undef ITER

  // epilogue: C/D layout col=lane&15, row=(lane>>4)*4+q
#pragma unroll
  for (int m = 0; m < 8; ++m) {
#pragma unroll
    for (int q = 0; q < 4; ++q) {
      int r = mt * 256 + wm * 128 + m * 16 + fg * 4 + q;
      if (gath != 0 && r >= cnt) continue;
      if (MODE == 1) {
        float wgt = topkw[rowmap[rowBase + r]];
        unsigned short* orow = outp + (size_t)(rowBase + r) * ncols;
#pragma unroll
        for (int n = 0; n < 4; ++n) {
          int col = nt * 128 + wn * 64 + n * 16 + fr;
          orow[col] = f2bf(wgt * (acc[m][n][q] + bias[col]));
        }
      } else {
        size_t orr = (gath ? (size_t)(rowBase + r) : (size_t)r) * (size_t)ncols;
        unsigned short* orow = outp + orr;
#pragma unroll
        for (int n = 0; n < 4; ++n) {
          int col = nt * 128 + wn * 64 + n * 16 + fr;
          orow[col] = f2bf(scale * gelu_fast(acc[m][n][q] + bias[col]));
        }
      }
    }
  }
}

// ---------------- LayerNorm (gathers shared + 2 expert slots, bf16 in) ----
__global__ void ln_kernel(const unsigned short* __restrict__ sh,
                          const unsigned short* __restrict__ acc2,
                          const int* __restrict__ inv,
                          const float* __restrict__ gamma,
                          const float* __restrict__ beta,
                          float* __restrict__ out) {
  int t = blockIdx.x, tid = threadIdx.x;
  int i0 = inv[t * 2 + 0], i1 = inv[t * 2 + 1];
  ushort4 a  = reinterpret_cast<const ushort4*>(sh   + (size_t)t  * DOUT)[tid];
  ushort4 c0 = reinterpret_cast<const ushort4*>(acc2 + (size_t)i0 * DOUT)[tid];
  ushort4 c1 = reinterpret_cast<const ushort4*>(acc2 + (size_t)i1 * DOUT)[tid];
  float4 v;
  v.x = bf2f(a.x) + bf2f(c0.x) + bf2f(c1.x);
  v.y = bf2f(a.y) + bf2f(c0.y) + bf2f(c1.y);
  v.z = bf2f(a.z) + bf2f(c0.z) + bf2f(c1.z);
  v.w = bf2f(a.w) + bf2f(c0.w) + bf2f(c1.w);
  float s = v.x + v.y + v.z + v.w;
  float q = v.x * v.x + v.y * v.y + v.z * v.z + v.w * v.w;
#pragma unroll
  for (int o = 32; o; o >>= 1) {
    s += __shfl_down(s, o);
    q += __shfl_down(q, o);
  }
  __shared__ float ss[4], sq[4];
  int w = tid >> 6, lane = tid & 63;
  if (lane == 0) { ss[w] = s; sq[w] = q; }
  __syncthreads();
  float S = ss[0] + ss[1] + ss[2] + ss[3];
  float Q = sq[0] + sq[1] + sq[2] + sq[3];
  float mean = S * (1.0f / DOUT);
  float var = Q * (1.0f / DOUT) - mean * mean;
  float inv_std = rsqrtf(var + 1e-5f);
  float4 g = reinterpret_cast<const float4*>(gamma)[tid];
  float4 b = reinterpret_cast<const float4*>(beta)[tid];
  float4 o;
  o.x = (v.x - mean) * inv_std * g.x + b.x;
  o.y = (v.y - mean) * inv_std * g.y + b.y;
  o.z = (v.z - mean) * inv_std * g.z + b.z;
  o.w = (v.w - mean) * inv_std * g.w + b.w;
  reinterpret_cast<float4*>(out + (size_t)t * DOUT)[tid] = o;
}

// ---------------- host ----------------
extern "C" void kernel_launch(void* const* d_in, const int* in_sizes, int n_in,
                              void* d_out, int out_size, void* d_ws, size_t ws_size,
                              hipStream_t stream) {
  const float* x       = (const float*)d_in[0];
  const float* W1      = (const float*)d_in[1];
  const float* b1      = (const float*)d_in[2];
  const float* W2      = (const float*)d_in[3];
  const float* b2      = (const float*)d_in[4];
  const float* gateW   = (const float*)d_in[5];
  const float* sharedW = (const float*)d_in[6];
  const float* sharedB = (const float*)d_in[7];
  const float* gamma   = (const float*)d_in[8];
  const float* beta    = (const float*)d_in[9];
  float* out = (float*)d_out;

  char* ws = (char*)d_ws;
  size_t off = 0;
  auto alloc = [&](size_t bytes) -> void* {
    void* p = ws + off;
    off += (bytes + 255) & ~(size_t)255;
    return p;
  };
  int*   offs      = (int*)alloc(9 * 4);
  int*   bc        = (int*)alloc(32 * 8 * 4);
  int*   blockbase = (int*)alloc(32 * 8 * 4);
  int*   topk_e = (int*)alloc((size_t)N_TOK * 2 * 4);
  float* topk_w = (float*)alloc((size_t)N_TOK * 2 * 4);
  int*   rowmap = (int*)alloc((size_t)N_TOK * 2 * 4);
  int*   inv    = (int*)alloc((size_t)N_TOK * 2 * 4);
  unsigned short* xbf  = (unsigned short*)alloc((size_t)N_TOK * DIM * 2);
  unsigned short* W1t  = (unsigned short*)alloc((size_t)NEXP * HID * DIM * 2);
  unsigned short* W2t  = (unsigned short*)alloc((size_t)NEXP * DOUT * HID * 2);
  unsigned short* sWt  = (unsigned short*)alloc((size_t)DOUT * DIM * 2);
  unsigned short* hbuf = (unsigned short*)alloc((size_t)N_TOK * 2 * HID * 2);
  unsigned short* acc2 = (unsigned short*)alloc((size_t)N_TOK * 2 * DOUT * 2);
  unsigned short* shbuf = (unsigned short*)alloc((size_t)N_TOK * DOUT * 2);
  if (off > ws_size) return;  // workspace too small -> fail validation loudly

  gate_kernel<<<N_TOK / 4, 256, 0, stream>>>(x, gateW, xbf, topk_e, topk_w);
  transpose_cast_kernel<<<8320, 256, 0, stream>>>(W1, W2, sharedW,
                                                  W1t, W2t, sWt);
  count_kernel<<<32, 256, 0, stream>>>(topk_e, bc);
  offsets_kernel<<<1, 256, 0, stream>>>(bc, offs, blockbase);
  scatter_kernel<<<32, 256, 0, stream>>>(topk_e, blockbase, rowmap, inv);

  // GEMM1 (experts, MT=16 x NT=32 per expert) + fused shared GEMM tail
  // (32 mt x 8 nt = 256 blocks). expGrid = 8*16*32 = 4096.
  gemm_mfma<0><<<NEXP * 16 * (HID / 128) + (N_TOK / 256) * (DOUT / 128), 256, 0, stream>>>(
      xbf, W1t, b1, hbuf, rowmap, offs, topk_w, DIM, HID, 16, HID / 128,
      NEXP * 16 * (HID / 128), sWt, sharedB, shbuf, N_TOK);
  // GEMM2: acc2[slot] = w * (h @ W2 + b2)   (compact, bf16, no atomics)
  gemm_mfma<1><<<NEXP * 16 * (DOUT / 128), 256, 0, stream>>>(
      hbuf, W2t, b2, acc2, rowmap, offs, topk_w, HID, DOUT, 16, DOUT / 128,
      0, nullptr, nullptr, nullptr, 0);
  // LayerNorm(shared + slot0 + slot1) -> out
  ln_kernel<<<N_TOK, 256, 0, stream>>>(shbuf, acc2, inv, gamma, beta, out);
}

// Round 17
// 520.923 us; speedup vs baseline: 1.0477x; 1.0477x over previous
//
#include <hip/hip_runtime.h>
#include <cstdint>
#include <cstddef>

#define N_TOK 8192
#define DIM   1024
#define HID   4096
#define DOUT  1024
#define NEXP  8

typedef short  s16x8 __attribute__((ext_vector_type(8)));
typedef __bf16 b16x8 __attribute__((ext_vector_type(8)));
typedef float  f32x4 __attribute__((ext_vector_type(4)));

__device__ __forceinline__ unsigned short f2bf(float f) {
  unsigned u = __float_as_uint(f);
  u += 0x7fffu + ((u >> 16) & 1u);
  return (unsigned short)(u >> 16);
}

__device__ __forceinline__ float bf2f(unsigned short u) {
  return __uint_as_float((unsigned)u << 16);
}

// tanh-form GELU via one fast exp: max |err| vs exact erf-GELU ~3e-4,
// 25x below bf16 quantization of h.
__device__ __forceinline__ float gelu_fast(float v) {
  float u2 = v * (1.5957691216f + 0.0713548163f * v * v);
  return v / (1.0f + __expf(-u2));
}

// async global->LDS, 16B per lane. LDS dest wave-uniform base; HW writes
// lane i at base + i*16. Global src is per-lane (enables source pre-swizzle).
__device__ __forceinline__ void gl_lds16(const void* g, void* l) {
  auto gp = (__attribute__((address_space(1))) void*)(reinterpret_cast<uintptr_t>(g));
  auto lp = (__attribute__((address_space(3))) void*)(reinterpret_cast<uintptr_t>(l));
  __builtin_amdgcn_global_load_lds(gp, lp, 16, 0, 0);
}

// ---------------- merged prep: gate [0,2048) + transpose [2048,10368) ------
// Gate: one wave/token, vectorized, no atomics (R15 body verbatim).
// Transpose: 128x64 tiles, 256B segments both sides (R15 body verbatim).
__global__ void prep_kernel(const float* __restrict__ x,
                            const float* __restrict__ gw,
                            const float* __restrict__ W1,
                            const float* __restrict__ W2,
                            const float* __restrict__ sW,
                            unsigned short* __restrict__ xbf,
                            int* __restrict__ topk_e,
                            float* __restrict__ topk_w,
                            unsigned short* __restrict__ W1t,
                            unsigned short* __restrict__ W2t,
                            unsigned short* __restrict__ sWt) {
  int bid = blockIdx.x;
  if (bid < 2048) {
    int w = threadIdx.x >> 6, lane = threadIdx.x & 63;
    int t = bid * 4 + w;
    const float4* xr = reinterpret_cast<const float4*>(x + (size_t)t * DIM);
    ushort4* xo = reinterpret_cast<ushort4*>(xbf + (size_t)t * DIM);
    float a0 = 0.f, a1 = 0.f, a2 = 0.f, a3 = 0.f;
    float a4 = 0.f, a5 = 0.f, a6 = 0.f, a7 = 0.f;
#pragma unroll
    for (int i = 0; i < 4; ++i) {
      int q = lane + (i << 6);
      float4 v = xr[q];
      ushort4 o;
      o.x = f2bf(v.x); o.y = f2bf(v.y); o.z = f2bf(v.z); o.w = f2bf(v.w);
      xo[q] = o;
      const float4* g = reinterpret_cast<const float4*>(gw + (size_t)q * 32);
      float4 g0 = g[0], g1 = g[1], g2 = g[2], g3 = g[3];
      float4 g4 = g[4], g5 = g[5], g6 = g[6], g7 = g[7];
      a0 += v.x * g0.x + v.y * g2.x + v.z * g4.x + v.w * g6.x;
      a1 += v.x * g0.y + v.y * g2.y + v.z * g4.y + v.w * g6.y;
      a2 += v.x * g0.z + v.y * g2.z + v.z * g4.z + v.w * g6.z;
      a3 += v.x * g0.w + v.y * g2.w + v.z * g4.w + v.w * g6.w;
      a4 += v.x * g1.x + v.y * g3.x + v.z * g5.x + v.w * g7.x;
      a5 += v.x * g1.y + v.y * g3.y + v.z * g5.y + v.w * g7.y;
      a6 += v.x * g1.z + v.y * g3.z + v.z * g5.z + v.w * g7.z;
      a7 += v.x * g1.w + v.y * g3.w + v.z * g5.w + v.w * g7.w;
    }
    float acc[8] = {a0, a1, a2, a3, a4, a5, a6, a7};
#pragma unroll
    for (int o = 32; o; o >>= 1)
#pragma unroll
      for (int e = 0; e < 8; ++e) acc[e] += __shfl_down(acc[e], o);
    if (lane == 0) {
      int e0 = 0;
#pragma unroll
      for (int e = 1; e < 8; ++e) if (acc[e] > acc[e0]) e0 = e;
      int e1 = -1;
#pragma unroll
      for (int e = 0; e < 8; ++e) {
        if (e == e0) continue;
        if (e1 < 0 || acc[e] > acc[e1]) e1 = e;
      }
      float w0 = 1.0f / (1.0f + expf(acc[e1] - acc[e0]));  // == p0/(p0+p1)
      topk_e[t * 2 + 0] = e0;
      topk_e[t * 2 + 1] = e1;
      topk_w[t * 2 + 0] = w0;
      topk_w[t * 2 + 1] = 1.0f - w0;
    }
    return;
  }
  bid -= 2048;
  const float* src;
  unsigned short* dst;
  int R, C, by, bx;
  if (bid < 4096) {                 // W1: [1024][4096], 8x64 tiles/expert
    int e = bid >> 9, t2 = bid & 511;
    src = W1 + (size_t)e * DIM * HID;
    dst = W1t + (size_t)e * DIM * HID;
    R = DIM; C = HID; by = t2 >> 6; bx = t2 & 63;
  } else if (bid < 8192) {          // W2: [4096][1024], 32x16 tiles/expert
    int b2 = bid - 4096;
    int e = b2 >> 9, t2 = b2 & 511;
    src = W2 + (size_t)e * HID * DOUT;
    dst = W2t + (size_t)e * HID * DOUT;
    R = HID; C = DOUT; by = t2 >> 4; bx = t2 & 15;
  } else {                          // sW: [1024][1024], 8x16 tiles
    int t2 = bid - 8192;
    src = sW; dst = sWt;
    R = DIM; C = DOUT; by = t2 >> 4; bx = t2 & 15;
  }
  int r0 = by * 128, c0 = bx * 64;

  __shared__ unsigned short tile[128][66];
  int t = threadIdx.x;

  const float* sp = src + (size_t)r0 * C + c0;
  int rr = t >> 4;
  int rc = (t & 15) * 4;
#pragma unroll
  for (int p = 0; p < 8; ++p) {
    int r = rr + p * 16;
    float4 v = *reinterpret_cast<const float4*>(sp + (size_t)r * C + rc);
    ushort4 o;
    o.x = f2bf(v.x); o.y = f2bf(v.y); o.z = f2bf(v.z); o.w = f2bf(v.w);
    *reinterpret_cast<ushort4*>(&tile[r][rc]) = o;
  }
  __syncthreads();

  unsigned short* dp = dst + (size_t)c0 * R + r0;
  int wc = t >> 5;
  int wr = (t & 31) * 4;
#pragma unroll
  for (int p = 0; p < 8; ++p) {
    int c = wc + p * 8;
    ushort4 o;
    o.x = tile[wr + 0][c];
    o.y = tile[wr + 1][c];
    o.z = tile[wr + 2][c];
    o.w = tile[wr + 3][c];
    *reinterpret_cast<ushort4*>(dp + (size_t)c * R + wr) = o;
  }
}

// per-block expert counts (LDS-privatized; zero global atomics)
__global__ void count_kernel(const int* __restrict__ topk_e,
                             int* __restrict__ bc) {  // [32][8]
  __shared__ int cnt[8];
  int t = threadIdx.x;
  if (t < 8) cnt[t] = 0;
  __syncthreads();
  int s = blockIdx.x * 512 + t * 2;
  atomicAdd(&cnt[topk_e[s]], 1);
  atomicAdd(&cnt[topk_e[s + 1]], 1);
  __syncthreads();
  if (t < 8) bc[blockIdx.x * 8 + t] = cnt[t];
}

// scan: per-expert offsets + absolute per-(block,expert) bases
__global__ void offsets_kernel(const int* __restrict__ bc,      // [32][8]
                               int* __restrict__ offs,          // [9]
                               int* __restrict__ blockbase) {   // [32][8]
  __shared__ int pre[32][8];
  __shared__ int tot[8];
  __shared__ int soff[9];
  int t = threadIdx.x;  // 256
  if (t < 8) {
    int run = 0;
    for (int b = 0; b < 32; ++b) { pre[b][t] = run; run += bc[b * 8 + t]; }
    tot[t] = run;
  }
  __syncthreads();
  if (t == 0) {
    int o = 0;
    for (int e = 0; e < 8; ++e) { soff[e] = o; offs[e] = o; o += tot[e]; }
    soff[8] = o; offs[8] = o;
  }
  __syncthreads();
  int b = t >> 3, e = t & 7;
  blockbase[t] = soff[e] + pre[b][e];
}

// scatter with LDS-local ranks (8 LDS counters/block; no global atomics)
__global__ void scatter_kernel(const int* __restrict__ topk_e,
                               const int* __restrict__ blockbase,
                               int* __restrict__ rowmap,
                               int* __restrict__ inv) {
  __shared__ int cnt[8];
  int t = threadIdx.x;
  if (t < 8) cnt[t] = 0;
  __syncthreads();
  int s = blockIdx.x * 512 + t * 2;
#pragma unroll
  for (int k = 0; k < 2; ++k) {
    int e = topk_e[s + k];
    int r = atomicAdd(&cnt[e], 1);  // LDS atomic (fast, block-local)
    int p = blockbase[blockIdx.x * 8 + e] + r;
    rowmap[p] = s + k;
    inv[s + k] = p;
  }
}

// ---------------- MFMA GEMM (256x128 tile, BK=32, 3-buffer ring, T2+T5) ---
// R17: reverted to the R14/R15 core (measured best: ~231 us/GEMM).
// 8 waves (4M x 2N), per-wave 64x64 output. K-loop unrolled x3 (ring
// period) -> compile-time buffer indices. Sync ledger (verified R13):
// per iter [stage(kt+2)] ; ds_reads(cur) ; MFMA ;
// "vmcnt(3) lgkmcnt(0)" (vmcnt(0) last 2 iters) ; s_barrier.
// T2 swizzle both-sides (zero bank conflicts); T5 setprio around MFMA.
// This structure is at its constrained optimum (R16: less LDS traffic
// costs occupancy; R10/R12: A-off-LDS costs L1 gather; R2/R3/R8/R9:
// schedule-invariant): ~600-660 TF effective.
// MODE 0: expert GEMM1 (gathered A rows, epi gelu->bf16) PLUS, for
//         bid >= expGrid, the dense shared GEMM (0.5*gelu->bf16) tail.
// MODE 1: expert GEMM2, compact A (h), epi: out[slot] = w*(acc+b2) -> bf16
template <int MODE>
__global__ __launch_bounds__(512, 4) void gemm_mfma(
    const unsigned short* __restrict__ A,
    const unsigned short* __restrict__ Ball,
    const float* __restrict__ biasAll,
    unsigned short* __restrict__ outAll,
    const int* __restrict__ rowmap,
    const int* __restrict__ offsets,
    const float* __restrict__ topkw,
    int K, int Ncols, int MT, int NT,
    int expGrid, const unsigned short* __restrict__ sB,
    const float* __restrict__ sBias, unsigned short* __restrict__ sOut,
    int M2) {
  int bid = blockIdx.x;
  int mt, nt, rowBase, cnt, ncols, gath;
  float scale;
  const unsigned short* Bp;
  const float* bias;
  unsigned short* outp;
  if (MODE == 0 && bid >= expGrid) {
    int b2 = bid - expGrid;
    int lg = (b2 & 7) * 32 + (b2 >> 3);
    mt = lg >> 3; nt = lg & 7;
    rowBase = 0; cnt = M2; gath = 0; scale = 0.5f;
    Bp = sB; bias = sBias; outp = sOut; ncols = DOUT;
  } else {
    int e = bid & 7;            // expert -> XCD pinning
    int idx = bid >> 3;
    if (MODE == 0) {
      int per = MT * 8;         // 8-nt band over all mt
      int band = idx / per;
      int r2 = idx - band * per;
      mt = r2 >> 3;
      nt = band * 8 + (r2 & 7);
      gath = 2; scale = 1.0f;
    } else {
      mt = idx >> 3; nt = idx & 7;  // NT == 8
      gath = 1; scale = 1.0f;
    }
    rowBase = offsets[e];
    cnt = offsets[e + 1] - rowBase;
    if (mt * 256 >= cnt) return;
    Bp = Ball + (size_t)e * Ncols * K;
    bias = biasAll + (size_t)e * Ncols;
    outp = outAll; ncols = Ncols;
  }

  int t = threadIdx.x;
  int w = t >> 6, lane = t & 63;
  int wm = w >> 1, wn = w & 1;      // 4 x 2 wave grid
  int fr = lane & 15, fg = lane >> 4;

  __shared__ __attribute__((aligned(16))) unsigned short As[3][256][32];
  __shared__ __attribute__((aligned(16))) unsigned short Bs[3][128][32];

  int srow = lane >> 2;
  int kch = ((lane & 3) ^ ((lane >> 3) & 3)) * 8;  // element offset (swz)
  int g0 = mt * 256 + w * 32 + srow;
  int g1 = g0 + 16;
  size_t ar0, ar1;
  {
    int c0 = g0 < cnt ? g0 : cnt - 1;
    int c1 = g1 < cnt ? g1 : cnt - 1;
    if (gath == 0)      { ar0 = (size_t)g0;                 ar1 = (size_t)g1; }
    else if (gath == 1) { ar0 = (size_t)(rowBase + c0);     ar1 = (size_t)(rowBase + c1); }
    else                { ar0 = (size_t)(rowmap[rowBase + c0] >> 1);
                          ar1 = (size_t)(rowmap[rowBase + c1] >> 1); }
  }
  const unsigned short* aS0 = A + ar0 * (size_t)K + kch;
  const unsigned short* aS1 = A + ar1 * (size_t)K + kch;
  const unsigned short* bS  = Bp + (size_t)(nt * 128 + w * 16 + srow) * K + kch;

  auto stage = [&](int buf, int kt) {
    int ko = kt * 32;
    gl_lds16(aS0 + ko, &As[buf][w * 32][0]);
    gl_lds16(aS1 + ko, &As[buf][w * 32 + 16][0]);
    gl_lds16(bS + ko, &Bs[buf][w * 16][0]);
  };

  f32x4 acc[4][4] = {};
  int KT = K >> 5;  // 32 or 128; both == 2 mod 3
  int swc = (fg ^ ((fr >> 1) & 3)) * 8;  // swizzled read chunk (elements)

#define ITER(CUR, NXT, KT_VAL)                                                 \
  {                                                                            \
    int kt_ = (KT_VAL);                                                        \
    if (kt_ + 2 < KT) stage(NXT, kt_ + 2);                                     \
    s16x8 af[4], bf[4];                                                        \
    _Pragma("unroll") for (int m = 0; m < 4; ++m)                              \
        af[m] = *reinterpret_cast<const s16x8*>(                               \
            &As[CUR][wm * 64 + m * 16 + fr][swc]);                             \
    _Pragma("unroll") for (int n = 0; n < 4; ++n)                              \
        bf[n] = *reinterpret_cast<const s16x8*>(                               \
            &Bs[CUR][wn * 64 + n * 16 + fr][swc]);                             \
    __builtin_amdgcn_s_setprio(1);                                             \
    _Pragma("unroll") for (int m = 0; m < 4; ++m)                              \
        _Pragma("unroll") for (int n = 0; n < 4; ++n)                          \
            acc[m][n] = __builtin_amdgcn_mfma_f32_16x16x32_bf16(               \
                __builtin_bit_cast(b16x8, af[m]),                              \
                __builtin_bit_cast(b16x8, bf[n]), acc[m][n], 0, 0, 0);         \
    __builtin_amdgcn_s_setprio(0);                                             \
    if (kt_ + 2 < KT)                                                          \
      asm volatile("s_waitcnt vmcnt(3) lgkmcnt(0)" ::: "memory");              \
    else                                                                       \
      asm volatile("s_waitcnt vmcnt(0) lgkmcnt(0)" ::: "memory");              \
    __builtin_amdgcn_s_barrier();                                              \
  }

  stage(0, 0);
  stage(1, 1);
  asm volatile("s_waitcnt vmcnt(3)" ::: "memory");
  __builtin_amdgcn_s_barrier();

  int kt = 0;
  for (; kt + 3 <= KT; kt += 3) {
    ITER(0, 2, kt)
    ITER(1, 0, kt + 1)
    ITER(2, 1, kt + 2)
  }
  ITER(0, 2, KT - 2)
  ITER(1, 0, KT - 1)
#undef ITER

  // epilogue: C/D layout col=lane&15, row=(lane>>4)*4+q
#pragma unroll
  for (int m = 0; m < 4; ++m) {
#pragma unroll
    for (int q = 0; q < 4; ++q) {
      int r = mt * 256 + wm * 64 + m * 16 + fg * 4 + q;
      if (gath != 0 && r >= cnt) continue;
      if (MODE == 1) {
        float wgt = topkw[rowmap[rowBase + r]];
        unsigned short* orow = outp + (size_t)(rowBase + r) * ncols;
#pragma unroll
        for (int n = 0; n < 4; ++n) {
          int col = nt * 128 + wn * 64 + n * 16 + fr;
          orow[col] = f2bf(wgt * (acc[m][n][q] + bias[col]));
        }
      } else {
        size_t orr = (gath ? (size_t)(rowBase + r) : (size_t)r) * (size_t)ncols;
        unsigned short* orow = outp + orr;
#pragma unroll
        for (int n = 0; n < 4; ++n) {
          int col = nt * 128 + wn * 64 + n * 16 + fr;
          orow[col] = f2bf(scale * gelu_fast(acc[m][n][q] + bias[col]));
        }
      }
    }
  }
}

// ---------------- LayerNorm (gathers shared + 2 expert slots, bf16 in) ----
__global__ void ln_kernel(const unsigned short* __restrict__ sh,
                          const unsigned short* __restrict__ acc2,
                          const int* __restrict__ inv,
                          const float* __restrict__ gamma,
                          const float* __restrict__ beta,
                          float* __restrict__ out) {
  int t = blockIdx.x, tid = threadIdx.x;
  int i0 = inv[t * 2 + 0], i1 = inv[t * 2 + 1];
  ushort4 a  = reinterpret_cast<const ushort4*>(sh   + (size_t)t  * DOUT)[tid];
  ushort4 c0 = reinterpret_cast<const ushort4*>(acc2 + (size_t)i0 * DOUT)[tid];
  ushort4 c1 = reinterpret_cast<const ushort4*>(acc2 + (size_t)i1 * DOUT)[tid];
  float4 v;
  v.x = bf2f(a.x) + bf2f(c0.x) + bf2f(c1.x);
  v.y = bf2f(a.y) + bf2f(c0.y) + bf2f(c1.y);
  v.z = bf2f(a.z) + bf2f(c0.z) + bf2f(c1.z);
  v.w = bf2f(a.w) + bf2f(c0.w) + bf2f(c1.w);
  float s = v.x + v.y + v.z + v.w;
  float q = v.x * v.x + v.y * v.y + v.z * v.z + v.w * v.w;
#pragma unroll
  for (int o = 32; o; o >>= 1) {
    s += __shfl_down(s, o);
    q += __shfl_down(q, o);
  }
  __shared__ float ss[4], sq[4];
  int w = tid >> 6, lane = tid & 63;
  if (lane == 0) { ss[w] = s; sq[w] = q; }
  __syncthreads();
  float S = ss[0] + ss[1] + ss[2] + ss[3];
  float Q = sq[0] + sq[1] + sq[2] + sq[3];
  float mean = S * (1.0f / DOUT);
  float var = Q * (1.0f / DOUT) - mean * mean;
  float inv_std = rsqrtf(var + 1e-5f);
  float4 g = reinterpret_cast<const float4*>(gamma)[tid];
  float4 b = reinterpret_cast<const float4*>(beta)[tid];
  float4 o;
  o.x = (v.x - mean) * inv_std * g.x + b.x;
  o.y = (v.y - mean) * inv_std * g.y + b.y;
  o.z = (v.z - mean) * inv_std * g.z + b.z;
  o.w = (v.w - mean) * inv_std * g.w + b.w;
  reinterpret_cast<float4*>(out + (size_t)t * DOUT)[tid] = o;
}

// ---------------- host ----------------
extern "C" void kernel_launch(void* const* d_in, const int* in_sizes, int n_in,
                              void* d_out, int out_size, void* d_ws, size_t ws_size,
                              hipStream_t stream) {
  const float* x       = (const float*)d_in[0];
  const float* W1      = (const float*)d_in[1];
  const float* b1      = (const float*)d_in[2];
  const float* W2      = (const float*)d_in[3];
  const float* b2      = (const float*)d_in[4];
  const float* gateW   = (const float*)d_in[5];
  const float* sharedW = (const float*)d_in[6];
  const float* sharedB = (const float*)d_in[7];
  const float* gamma   = (const float*)d_in[8];
  const float* beta    = (const float*)d_in[9];
  float* out = (float*)d_out;

  char* ws = (char*)d_ws;
  size_t off = 0;
  auto alloc = [&](size_t bytes) -> void* {
    void* p = ws + off;
    off += (bytes + 255) & ~(size_t)255;
    return p;
  };
  int*   offs      = (int*)alloc(9 * 4);
  int*   bc        = (int*)alloc(32 * 8 * 4);
  int*   blockbase = (int*)alloc(32 * 8 * 4);
  int*   topk_e = (int*)alloc((size_t)N_TOK * 2 * 4);
  float* topk_w = (float*)alloc((size_t)N_TOK * 2 * 4);
  int*   rowmap = (int*)alloc((size_t)N_TOK * 2 * 4);
  int*   inv    = (int*)alloc((size_t)N_TOK * 2 * 4);
  unsigned short* xbf  = (unsigned short*)alloc((size_t)N_TOK * DIM * 2);
  unsigned short* W1t  = (unsigned short*)alloc((size_t)NEXP * HID * DIM * 2);
  unsigned short* W2t  = (unsigned short*)alloc((size_t)NEXP * DOUT * HID * 2);
  unsigned short* sWt  = (unsigned short*)alloc((size_t)DOUT * DIM * 2);
  unsigned short* hbuf = (unsigned short*)alloc((size_t)N_TOK * 2 * HID * 2);
  unsigned short* acc2 = (unsigned short*)alloc((size_t)N_TOK * 2 * DOUT * 2);
  unsigned short* shbuf = (unsigned short*)alloc((size_t)N_TOK * DOUT * 2);
  if (off > ws_size) return;  // workspace too small -> fail validation loudly

  // merged gate (2048) + transpose (8320) in one dispatch
  prep_kernel<<<2048 + 8320, 256, 0, stream>>>(x, gateW, W1, W2, sharedW,
                                               xbf, topk_e, topk_w,
                                               W1t, W2t, sWt);
  count_kernel<<<32, 256, 0, stream>>>(topk_e, bc);
  offsets_kernel<<<1, 256, 0, stream>>>(bc, offs, blockbase);
  scatter_kernel<<<32, 256, 0, stream>>>(topk_e, blockbase, rowmap, inv);

  // GEMM1 (experts, MT=16 x NT=32 per expert) + fused shared GEMM tail
  // (32 mt x 8 nt = 256 blocks). expGrid = 8*16*32 = 4096.
  gemm_mfma<0><<<NEXP * 16 * (HID / 128) + (N_TOK / 256) * (DOUT / 128), 512, 0, stream>>>(
      xbf, W1t, b1, hbuf, rowmap, offs, topk_w, DIM, HID, 16, HID / 128,
      NEXP * 16 * (HID / 128), sWt, sharedB, shbuf, N_TOK);
  // GEMM2: acc2[slot] = w * (h @ W2 + b2)   (compact, bf16, no atomics)
  gemm_mfma<1><<<NEXP * 16 * (DOUT / 128), 512, 0, stream>>>(
      hbuf, W2t, b2, acc2, rowmap, offs, topk_w, HID, DOUT, 16, DOUT / 128,
      0, nullptr, nullptr, nullptr, 0);
  // LayerNorm(shared + slot0 + slot1) -> out
  ln_kernel<<<N_TOK, 256, 0, stream>>>(shbuf, acc2, inv, gamma, beta, out);
}